// Round 6
// baseline (175.555 us; speedup 1.0000x reference)
//
#include <hip/hip_runtime.h>

typedef int i32x4 __attribute__((ext_vector_type(4)));

#define QMAXF 127.0f

#define LGKM0() asm volatile("s_waitcnt lgkmcnt(0)" ::: "memory")
#define SCHED0() __builtin_amdgcn_sched_barrier(0)
// lgkm drain (ds_writes visible) -> barrier -> fence against hoisting next reads
#define BARX() do { LGKM0(); __builtin_amdgcn_s_barrier(); SCHED0(); } while (0)

// ---------------------------------------------------------------------------
// Weight quantization: one block per output row (cout). ~2 us. Exact IEEE div.
// ---------------------------------------------------------------------------
__global__ __launch_bounds__(256) void quant_w_kernel(
    const float* __restrict__ w, const float* __restrict__ act_scale,
    signed char* __restrict__ qw, float* __restrict__ wscale)
{
    const int row = blockIdx.x;
    const int t   = threadIdx.x;
    const float s = act_scale[0];

    float4 v = *reinterpret_cast<const float4*>(w + (size_t)row * 1024 + t * 4);
    float a0 = v.x * s, a1 = v.y * s, a2 = v.z * s, a3 = v.w * s;
    float m = fmaxf(fmaxf(fabsf(a0), fabsf(a1)), fmaxf(fabsf(a2), fabsf(a3)));

    #pragma unroll
    for (int i = 1; i < 64; i <<= 1)
        m = fmaxf(m, __shfl_xor(m, i));

    __shared__ float wmax[4];
    if ((t & 63) == 0) wmax[t >> 6] = m;
    __syncthreads();
    m = fmaxf(fmaxf(wmax[0], wmax[1]), fmaxf(wmax[2], wmax[3]));

    const float wsc = m / QMAXF;

    int q0 = (int)rintf(a0 / wsc);
    int q1 = (int)rintf(a1 / wsc);
    int q2 = (int)rintf(a2 / wsc);
    int q3 = (int)rintf(a3 / wsc);
    int packed = (q0 & 255) | ((q1 & 255) << 8) | ((q2 & 255) << 16) | ((q3 & 255) << 24);
    reinterpret_cast<int*>(qw)[row * 256 + t] = packed;

    if (t == 0) wscale[row] = wsc;
}

// ---------------------------------------------------------------------------
// Persistent-B fused kernel.
//  grid = 256 blocks (1/CU): block b -> n-strip n0=(b&7)*128 (XCD-aligned),
//  m-chunk rows [(b>>3)*M/32, +M/32).
//  B strip (128 x 1024 int8 = 128 KB) staged into LDS ONCE via global_load_lds
//  (global source pre-swizzled slot^=(row&7); linear LDS dest; reads re-apply).
//  Then per 128-row A-subtile: K-steps of 64, A f32 loaded to regs (depth-2
//  prefetch), quantized in-register (x * (1/s) — see error analysis in notes),
//  ds_write into stride-80 double buffer (conflict-free), 8 mfma/wave/step.
//  Raw s_barrier + lgkmcnt(0): A-prefetch global loads stay in flight across
//  barriers (counted vmcnt left to the compiler's dependency tracking).
// ---------------------------------------------------------------------------
__global__ __launch_bounds__(512, 2) void gemm_fused_kernel(
    const float* __restrict__ x, const signed char* __restrict__ qw,
    const float* __restrict__ act_scale, const float* __restrict__ wscale,
    const float* __restrict__ bias, float* __restrict__ out, int M)
{
    __shared__ __align__(16) signed char Bs[128 * 1024];   // 128 KB persistent
    __shared__ __align__(16) signed char As[2][128 * 80];  // 20 KB dbuf, stride 80

    const int t    = threadIdx.x;
    const int lane = t & 63;
    const int w    = t >> 6;        // wave 0..7: rows (w>>2)*64, cols (w&3)*32
    const int lrow = lane & 15;
    const int ks   = lane >> 4;     // 16B K-slot 0..3
    const int arow = t >> 2;        // A-stage row 0..127
    const int ac   = t & 3;         // A-stage 16-elem chunk 0..3

    const int bid   = blockIdx.x;
    const int n0    = (bid & 7) * 128;
    const int rbase = (bid >> 3) * (M >> 5);
    const int nsub  = (M >> 5) >> 7;           // subtiles per chunk (M=32768 -> 8)

    const float s    = act_scale[0];
    const float rinv = 1.0f / s;

    float wsv[2], bv[2]; int gnc[2];
    #pragma unroll
    for (int nf = 0; nf < 2; ++nf) {
        const int gn = n0 + (w & 3) * 32 + nf * 16 + lrow;
        gnc[nf] = gn; wsv[nf] = wscale[gn]; bv[nf] = bias[gn];
    }

    auto LOADA = [&](int r0, int kt, float4 (&a)[4]) {
        const float* p = x + (size_t)(r0 + arow) * 1024 + kt * 64 + ac * 16;
        a[0] = *reinterpret_cast<const float4*>(p);
        a[1] = *reinterpret_cast<const float4*>(p + 4);
        a[2] = *reinterpret_cast<const float4*>(p + 8);
        a[3] = *reinterpret_cast<const float4*>(p + 12);
    };
    auto QUANTW = [&](const float4 (&a)[4], int buf) {
        int pk[4];
        #pragma unroll
        for (int c = 0; c < 4; ++c) {
            int q0 = (int)rintf(fminf(fmaxf(a[c].x * rinv, -QMAXF), QMAXF));
            int q1 = (int)rintf(fminf(fmaxf(a[c].y * rinv, -QMAXF), QMAXF));
            int q2 = (int)rintf(fminf(fmaxf(a[c].z * rinv, -QMAXF), QMAXF));
            int q3 = (int)rintf(fminf(fmaxf(a[c].w * rinv, -QMAXF), QMAXF));
            pk[c] = (q0 & 255) | ((q1 & 255) << 8) | ((q2 & 255) << 16) | ((q3 & 255) << 24);
        }
        *reinterpret_cast<i32x4*>(&As[buf][arow * 80 + ac * 16]) =
            i32x4{pk[0], pk[1], pk[2], pk[3]};
    };
    auto READ_AB = [&](int buf, int kt, i32x4 (&Af)[4], i32x4 (&Bf)[2]) {
        #pragma unroll
        for (int mf = 0; mf < 4; ++mf) {
            const int row = (w >> 2) * 64 + mf * 16 + lrow;
            Af[mf] = *reinterpret_cast<const i32x4*>(&As[buf][row * 80 + ks * 16]);
        }
        #pragma unroll
        for (int nf = 0; nf < 2; ++nf) {
            const int row = (w & 3) * 32 + nf * 16 + lrow;
            const int sp  = (kt * 4 + ks) ^ (row & 7);
            Bf[nf] = *reinterpret_cast<const i32x4*>(&Bs[row * 1024 + sp * 16]);
        }
    };
    auto STAGE_B = [&]() {
        #pragma unroll
        for (int j = 0; j < 16; ++j) {
            const int unit = j * 512 + t;      // wave-contig: dst = base + lane*16
            const int r  = unit >> 6;
            const int sp = unit & 63;
            const int sg = sp ^ (r & 7);       // pre-swizzled global source slot
            const signed char* src = qw + (size_t)(n0 + r) * 1024 + sg * 16;
            __builtin_amdgcn_global_load_lds(
                (const __attribute__((address_space(1))) void*)src,
                (__attribute__((address_space(3))) void*)(Bs + unit * 16), 16, 0, 0);
        }
    };

    for (int ms = 0; ms < nsub; ++ms) {
        const int r0 = rbase + ms * 128;
        i32x4 acc[4][2] = {};
        float4 A0[4], A1[4];

        LOADA(r0, 0, A0);
        LOADA(r0, 1, A1);
        if (ms == 0) {
            STAGE_B();
            QUANTW(A0, 0);       // waits its own loads (and B, once — prologue)
            __syncthreads();     // full drain: Bs + As[0] ready
        } else {
            QUANTW(A0, 0);       // vmcnt-counted wait on A0 only; A1 in flight
            BARX();
        }

        #pragma unroll
        for (int kh = 0; kh < 8; ++kh) {
            const int kt = 2 * kh;
            i32x4 Af[4], Bf[2];

            // even phase: compute kt from buf0; prefetch kt+2; quant kt+1 -> buf1
            if (kt + 2 < 16) LOADA(r0, kt + 2, A0);
            READ_AB(0, kt, Af, Bf);
            LGKM0(); SCHED0();
            __builtin_amdgcn_s_setprio(1);
            #pragma unroll
            for (int mf = 0; mf < 4; ++mf)
                #pragma unroll
                for (int nf = 0; nf < 2; ++nf)
                    acc[mf][nf] = __builtin_amdgcn_mfma_i32_16x16x64_i8(
                        Af[mf], Bf[nf], acc[mf][nf], 0, 0, 0);
            __builtin_amdgcn_s_setprio(0);
            QUANTW(A1, 1);
            BARX();

            // odd phase: compute kt+1 from buf1; prefetch kt+3; quant kt+2 -> buf0
            if (kt + 3 < 16) LOADA(r0, kt + 3, A1);
            READ_AB(1, kt + 1, Af, Bf);
            LGKM0(); SCHED0();
            __builtin_amdgcn_s_setprio(1);
            #pragma unroll
            for (int mf = 0; mf < 4; ++mf)
                #pragma unroll
                for (int nf = 0; nf < 2; ++nf)
                    acc[mf][nf] = __builtin_amdgcn_mfma_i32_16x16x64_i8(
                        Af[mf], Bf[nf], acc[mf][nf], 0, 0, 0);
            __builtin_amdgcn_s_setprio(0);
            if (kt + 2 < 16) QUANTW(A0, 0);
            BARX();
        }

        // epilogue: dequant + bias, stream out this 128x128 subtile
        #pragma unroll
        for (int mf = 0; mf < 4; ++mf) {
            #pragma unroll
            for (int rr = 0; rr < 4; ++rr) {
                const int gm = r0 + (w >> 2) * 64 + mf * 16 + ks * 4 + rr;
                float* orow = out + (size_t)gm * 1024;
                #pragma unroll
                for (int nf = 0; nf < 2; ++nf)
                    orow[gnc[nf]] = (float)acc[mf][nf][rr] * wsv[nf] + bv[nf];
            }
        }
    }
}

// ---------------------------------------------------------------------------
extern "C" void kernel_launch(void* const* d_in, const int* in_sizes, int n_in,
                              void* d_out, int out_size, void* d_ws, size_t ws_size,
                              hipStream_t stream)
{
    const float* x         = (const float*)d_in[0];
    const float* weight    = (const float*)d_in[1];
    const float* bias      = (const float*)d_in[2];
    const float* act_scale = (const float*)d_in[3];
    float* out             = (float*)d_out;

    const int K = 1024;
    const int N = 1024;
    const int M = in_sizes[0] / K;   // 32768

    // workspace: qw (N*K int8) | wscale (N f32)
    char* wsb = (char*)d_ws;
    signed char* qw  = (signed char*)wsb;
    float*       wsc = (float*)(wsb + (size_t)N * K);

    quant_w_kernel<<<N, 256, 0, stream>>>(weight, act_scale, qw, wsc);
    gemm_fused_kernel<<<256, 512, 0, stream>>>(x, qw, act_scale, wsc, bias, out, M);
}